// Round 13
// baseline (266.058 us; speedup 1.0000x reference)
//
#include <hip/hip_runtime.h>
#include <hip/hip_bf16.h>

#define AS1 __attribute__((address_space(1)))
#define AS3 __attribute__((address_space(3)))

typedef __attribute__((ext_vector_type(4))) float floatx4;
typedef __attribute__((ext_vector_type(8))) short bf16x8;
typedef unsigned short u16;
typedef unsigned int u32;

// ---- bf16 helpers ----
__device__ __forceinline__ u16 f2b(float f) {  // RNE
  u32 u = __builtin_bit_cast(u32, f);
  u += 0x7fffu + ((u >> 16) & 1u);
  return (u16)(u >> 16);
}
__device__ __forceinline__ u32 pk2(float lo, float hi) {
  __hip_bfloat162 h = __float22bfloat162_rn(float2{lo, hi});
  u32 u;
  __builtin_memcpy(&u, &h, 4);
  return u;
}
__device__ __forceinline__ bf16x8 cvt8(float4 a, float4 b) {
  uint4 u{pk2(a.x, a.y), pk2(a.z, a.w), pk2(b.x, b.y), pk2(b.z, b.w)};
  return __builtin_bit_cast(bf16x8, u);
}

__device__ __forceinline__ void gld16(const void* g, AS3 u32* l) {
  __builtin_amdgcn_global_load_lds((const AS1 u32*)(const AS1 void*)g, l, 16,
                                   0, 0);
}

// ================= bulk f32 -> bf16 conversion (x + 4 weights) ==============
__global__ __launch_bounds__(256) void cvt_all(
    const float* __restrict__ x, const float* __restrict__ wq,
    const float* __restrict__ wk, const float* __restrict__ wv,
    const float* __restrict__ wo, u16* __restrict__ xb, u16* __restrict__ wqb,
    u16* __restrict__ wkb, u16* __restrict__ wvb, u16* __restrict__ wob) {
  const int i = blockIdx.x * 256 + threadIdx.x;  // handles 8 elems
  const float* src;
  u16* dst;
  int off;
  if (i < 524288) {
    src = x; dst = xb; off = i;
  } else {
    const int j = i - 524288;
    const int wsel = j >> 17;
    off = j & 131071;
    src = (wsel == 0) ? wq : (wsel == 1) ? wk : (wsel == 2) ? wv : wo;
    dst = (wsel == 0) ? wqb : (wsel == 1) ? wkb : (wsel == 2) ? wvb : wob;
  }
  const float4* p = (const float4*)(src + (size_t)off * 8);
  *(bf16x8*)(dst + (size_t)off * 8) = cvt8(p[0], p[1]);
}

// ====== bf16 128x128 GEMM mainloop (m97 pattern): global_load_lds w=16 ======
// A,B bf16 row-major stride 1024. BK=32, unpadded 32-u16 LDS rows.
__device__ __forceinline__ void gemm_bf16(const u16* __restrict__ A,
                                          const u16* __restrict__ B, short* sA,
                                          short* sB, floatx4 acc[4][4]) {
  const int tid = threadIdx.x;
  const int lane = tid & 63;
  const int w = tid >> 6;
  const int l15 = lane & 15, quad = lane >> 4;
  const int wm = w >> 1, wn = w & 1;

  // wave w stages rows [w*32, w*32+32): 2 chunks of 16 rows, lane covers
  // row lane>>2, 16B piece lane&3 (matches HW lane*16 LDS placement).
  const u16* ga = A + ((size_t)(w * 32 + (lane >> 2))) * 1024 + (lane & 3) * 8;
  const u16* gb = B + ((size_t)(w * 32 + (lane >> 2))) * 1024 + (lane & 3) * 8;
  AS3 u32* la = (AS3 u32*)(AS3 short*)sA + w * 512;
  AS3 u32* lb = (AS3 u32*)(AS3 short*)sB + w * 512;

  for (int kt = 0; kt < 32; ++kt) {
    __syncthreads();  // prior fragment reads complete
    gld16(ga, la);
    gld16(ga + (size_t)16 * 1024, la + 256);
    gld16(gb, lb);
    gld16(gb + (size_t)16 * 1024, lb + 256);
    ga += 32;
    gb += 32;
    __syncthreads();  // staging drained (vmcnt before barrier)

    bf16x8 af[4], bfr[4];
#pragma unroll
    for (int mc = 0; mc < 4; ++mc)
      af[mc] = *(const bf16x8*)&sA[(wm * 64 + mc * 16 + l15) * 32 + quad * 8];
#pragma unroll
    for (int nc = 0; nc < 4; ++nc)
      bfr[nc] = *(const bf16x8*)&sB[(wn * 64 + nc * 16 + l15) * 32 + quad * 8];
#pragma unroll
    for (int mc = 0; mc < 4; ++mc)
#pragma unroll
      for (int nc = 0; nc < 4; ++nc)
        acc[mc][nc] = __builtin_amdgcn_mfma_f32_16x16x32_bf16(
            af[mc], bfr[nc], acc[mc][nc], 0, 0, 0);
  }
}

// ---------------- QKV epilogue (shared by both paths) -----------------------
__device__ __forceinline__ void qkv_epilogue(floatx4 acc[4][4], int m0, int nb,
                                             int sel, u16* __restrict__ Q,
                                             u16* __restrict__ K,
                                             u16* __restrict__ Vt) {
  const int tid = threadIdx.x;
  const int lane = tid & 63, w = tid >> 6;
  const int l15 = lane & 15, quad = lane >> 4;
  const int wm = w >> 1, wn = w & 1;
#pragma unroll
  for (int mc = 0; mc < 4; ++mc) {
#pragma unroll
    for (int nc = 0; nc < 4; ++nc) {
      const int nn = nb + wn * 64 + nc * 16 + l15;
      const int h = nn >> 6, d = nn & 63;
#pragma unroll
      for (int r = 0; r < 4; ++r) {
        const int m = m0 + wm * 64 + mc * 16 + quad * 4 + r;
        const int b = m >> 11, s = m & 2047;
        const int bh = b * 16 + h;
        const u16 v = f2b(acc[mc][nc][r]);
        if (sel == 0)
          Q[((size_t)bh * 2048 + s) * 64 + d] = v;
        else if (sel == 1)
          K[((size_t)bh * 2048 + s) * 64 + d] = v;
        else
          Vt[((size_t)bh * 64 + d) * 2048 + s] = v;
      }
    }
  }
}

__global__ __launch_bounds__(256) void qkv_gemm_b(
    const u16* __restrict__ xb, const u16* __restrict__ Wqb,
    const u16* __restrict__ Wkb, const u16* __restrict__ Wvb,
    u16* __restrict__ Q, u16* __restrict__ K, u16* __restrict__ Vt) {
  __shared__ __align__(16) short smem[2 * 128 * 32];
  const int m0 = blockIdx.x * 128;
  const int by = blockIdx.y;
  const int sel = by >> 3;
  const int nb = (by & 7) * 128;
  const u16* W = (sel == 0) ? Wqb : (sel == 1) ? Wkb : Wvb;

  floatx4 acc[4][4];
#pragma unroll
  for (int i = 0; i < 4; i++)
#pragma unroll
    for (int j = 0; j < 4; j++) acc[i][j] = (floatx4)0.0f;
  gemm_bf16(xb + (size_t)m0 * 1024, W + (size_t)nb * 1024, smem,
            smem + 128 * 32, acc);
  qkv_epilogue(acc, m0, nb, sel, Q, K, Vt);
}

__global__ __launch_bounds__(256) void out_gemm_b(const u16* __restrict__ ctx,
                                                  const u16* __restrict__ Wob,
                                                  const float* __restrict__ bo,
                                                  float* __restrict__ out) {
  __shared__ __align__(16) short smem[2 * 128 * 32];
  const int tid = threadIdx.x;
  const int lane = tid & 63, w = tid >> 6;
  const int l15 = lane & 15, quad = lane >> 4;
  const int wm = w >> 1, wn = w & 1;
  const int m0 = blockIdx.x * 128;
  const int n0 = blockIdx.y * 128;

  floatx4 acc[4][4];
#pragma unroll
  for (int i = 0; i < 4; i++)
#pragma unroll
    for (int j = 0; j < 4; j++) acc[i][j] = (floatx4)0.0f;
  gemm_bf16(ctx + (size_t)m0 * 1024, Wob + (size_t)n0 * 1024, smem,
            smem + 128 * 32, acc);

#pragma unroll
  for (int mc = 0; mc < 4; ++mc)
#pragma unroll
    for (int nc = 0; nc < 4; ++nc) {
      const int n = n0 + wn * 64 + nc * 16 + l15;
      const float bias = bo[n];
#pragma unroll
      for (int r = 0; r < 4; ++r) {
        const int m = m0 + wm * 64 + mc * 16 + quad * 4 + r;
        out[(size_t)m * 1024 + n] = acc[mc][nc][r] + bias;
      }
    }
}

// ============ Fallback f32-staging 128x128 GEMM (round-12, verified) ========
template <bool F32A>
__device__ __forceinline__ void gemm128(const void* __restrict__ A,
                                        const float* __restrict__ B, short* sA,
                                        short* sB, floatx4 acc[4][4]) {
  const int tid = threadIdx.x;
  const int lane = tid & 63;
  const int w = tid >> 6;
  const int l15 = lane & 15, quad = lane >> 4;
  const int wm = w >> 1, wn = w & 1;
  const int srow = tid >> 1;
  const int scb = (tid & 1) * 16;

  float4 pa[4], pb[4];
  int4 pa16[2];
  if constexpr (F32A) {
    const float* ap = (const float*)A + (size_t)srow * 1024 + scb;
    pa[0] = ((const float4*)ap)[0]; pa[1] = ((const float4*)ap)[1];
    pa[2] = ((const float4*)ap)[2]; pa[3] = ((const float4*)ap)[3];
  } else {
    const u16* ap = (const u16*)A + (size_t)srow * 1024 + scb;
    pa16[0] = ((const int4*)ap)[0]; pa16[1] = ((const int4*)ap)[1];
  }
  {
    const float* bp = B + (size_t)srow * 1024 + scb;
    pb[0] = ((const float4*)bp)[0]; pb[1] = ((const float4*)bp)[1];
    pb[2] = ((const float4*)bp)[2]; pb[3] = ((const float4*)bp)[3];
  }

  for (int kt = 0; kt < 32; ++kt) {
    __syncthreads();
    if constexpr (F32A) {
      *(bf16x8*)&sA[srow * 40 + scb] = cvt8(pa[0], pa[1]);
      *(bf16x8*)&sA[srow * 40 + scb + 8] = cvt8(pa[2], pa[3]);
    } else {
      *(int4*)&sA[srow * 40 + scb] = pa16[0];
      *(int4*)&sA[srow * 40 + scb + 8] = pa16[1];
    }
    *(bf16x8*)&sB[srow * 40 + scb] = cvt8(pb[0], pb[1]);
    *(bf16x8*)&sB[srow * 40 + scb + 8] = cvt8(pb[2], pb[3]);
    __syncthreads();

    if (kt < 31) {
      const int k0 = (kt + 1) * 32;
      if constexpr (F32A) {
        const float* ap = (const float*)A + (size_t)srow * 1024 + k0 + scb;
        pa[0] = ((const float4*)ap)[0]; pa[1] = ((const float4*)ap)[1];
        pa[2] = ((const float4*)ap)[2]; pa[3] = ((const float4*)ap)[3];
      } else {
        const u16* ap = (const u16*)A + (size_t)srow * 1024 + k0 + scb;
        pa16[0] = ((const int4*)ap)[0]; pa16[1] = ((const int4*)ap)[1];
      }
      const float* bp = B + (size_t)srow * 1024 + k0 + scb;
      pb[0] = ((const float4*)bp)[0]; pb[1] = ((const float4*)bp)[1];
      pb[2] = ((const float4*)bp)[2]; pb[3] = ((const float4*)bp)[3];
    }

    bf16x8 af[4], bfr[4];
#pragma unroll
    for (int mc = 0; mc < 4; ++mc)
      af[mc] = *(const bf16x8*)&sA[(wm * 64 + mc * 16 + l15) * 40 + quad * 8];
#pragma unroll
    for (int nc = 0; nc < 4; ++nc)
      bfr[nc] = *(const bf16x8*)&sB[(wn * 64 + nc * 16 + l15) * 40 + quad * 8];
#pragma unroll
    for (int mc = 0; mc < 4; ++mc)
#pragma unroll
      for (int nc = 0; nc < 4; ++nc)
        acc[mc][nc] = __builtin_amdgcn_mfma_f32_16x16x32_bf16(
            af[mc], bfr[nc], acc[mc][nc], 0, 0, 0);
  }
}

__global__ __launch_bounds__(256) void qkv_gemm_f(
    const float* __restrict__ x, const float* __restrict__ Wq,
    const float* __restrict__ Wk, const float* __restrict__ Wv,
    u16* __restrict__ Q, u16* __restrict__ K, u16* __restrict__ Vt) {
  __shared__ __align__(16) short smem[2 * 128 * 40];
  const int m0 = blockIdx.x * 128;
  const int by = blockIdx.y;
  const int sel = by >> 3;
  const int nb = (by & 7) * 128;
  const float* W = (sel == 0) ? Wq : (sel == 1) ? Wk : Wv;

  floatx4 acc[4][4];
#pragma unroll
  for (int i = 0; i < 4; i++)
#pragma unroll
    for (int j = 0; j < 4; j++) acc[i][j] = (floatx4)0.0f;
  gemm128<true>((const void*)(x + (size_t)m0 * 1024), W + (size_t)nb * 1024,
                smem, smem + 128 * 40, acc);
  qkv_epilogue(acc, m0, nb, sel, Q, K, Vt);
}

__global__ __launch_bounds__(256) void out_gemm_f(const u16* __restrict__ ctx,
                                                  const float* __restrict__ Wo,
                                                  const float* __restrict__ bo,
                                                  float* __restrict__ out) {
  __shared__ __align__(16) short smem[2 * 128 * 40];
  const int tid = threadIdx.x;
  const int lane = tid & 63, w = tid >> 6;
  const int l15 = lane & 15, quad = lane >> 4;
  const int wm = w >> 1, wn = w & 1;
  const int m0 = blockIdx.x * 128;
  const int n0 = blockIdx.y * 128;

  floatx4 acc[4][4];
#pragma unroll
  for (int i = 0; i < 4; i++)
#pragma unroll
    for (int j = 0; j < 4; j++) acc[i][j] = (floatx4)0.0f;
  gemm128<false>((const void*)(ctx + (size_t)m0 * 1024),
                 Wo + (size_t)n0 * 1024, smem, smem + 128 * 40, acc);

#pragma unroll
  for (int mc = 0; mc < 4; ++mc)
#pragma unroll
    for (int nc = 0; nc < 4; ++nc) {
      const int n = n0 + wn * 64 + nc * 16 + l15;
      const float bias = bo[n];
#pragma unroll
      for (int r = 0; r < 4; ++r) {
        const int m = m0 + wm * 64 + mc * 16 + quad * 4 + r;
        out[(size_t)m * 1024 + n] = acc[mc][nc][r] + bias;
      }
    }
}

// ============== Kernel: causal flash attention (transposed scores) ==========
// grid 1024: qb=31-(bid>>5) (long first), bh=bid&31. 64 q/block, 16 q/wave.
// Super-tiles of 128 keys. St = K*Q^T -> C-layout(col=q,row=k) IS the PV
// B-operand (P^T) -> no LDS round-trip. PV via zero-padded K=32 MFMA
// (exact K=16 emulation). Fixed-shift softmax (C=10), sums add linearly.
__global__ __launch_bounds__(256, 4) void attn_kernel(
    const u16* __restrict__ Q, const u16* __restrict__ K,
    const u16* __restrict__ Vt, u16* __restrict__ ctx) {
  const int bid = blockIdx.x;
  const int qb = 31 - (bid >> 5);
  const int bh = bid & 31;
  const int tid = threadIdx.x;
  const int w = tid >> 6;
  const int lane = tid & 63;
  const int l15 = lane & 15;
  const int quad = lane >> 4;

  __shared__ __align__(16) u16 sK[128 * 72];   // [key][d], pad 72
  __shared__ __align__(16) u16 sV[64 * 136];   // [d][key], pad 136

  const int q0 = qb * 64;
  const int wrow = q0 + w * 16;  // wave's 16 q rows

  bf16x8 aq0, aq1;
  {
    const u16* qp = Q + ((size_t)bh * 2048 + wrow + l15) * 64 + quad * 8;
    aq0 = *(const bf16x8*)(qp);
    aq1 = *(const bf16x8*)(qp + 32);
  }

  floatx4 accOT[4];  // O^T: [d-tile][4]; col=q=l15, row=d=quad*4+r
#pragma unroll
  for (int i = 0; i < 4; ++i) accOT[i] = (floatx4)0.0f;
  float lsum = 0.0f;  // partial row-sum for q=l15 (this quad's k rows)

  const int jbmax = (q0 + 63) >> 7;
  const int kr = tid >> 1, kc = (tid & 1) * 32;   // K staging
  const int vd = tid >> 2, vc = (tid & 3) * 32;   // V staging

  int4 pk[4], pv[4];
#pragma unroll
  for (int i = 0; i < 4; ++i) {
    pk[i] = *(const int4*)(K + ((size_t)bh * 2048 + kr) * 64 + kc + i * 8);
    pv[i] = *(const int4*)(Vt + ((size_t)bh * 64 + vd) * 2048 + vc + i * 8);
  }

  for (int jb = 0; jb <= jbmax; ++jb) {
    __syncthreads();  // prior tile reads complete
#pragma unroll
    for (int i = 0; i < 4; ++i) {
      *(int4*)&sK[kr * 72 + kc + i * 8] = pk[i];
      *(int4*)&sV[vd * 136 + vc + i * 8] = pv[i];
    }
    __syncthreads();  // staging visible
    if (jb < jbmax) {
      const int jn = (jb + 1) * 128;
#pragma unroll
      for (int i = 0; i < 4; ++i) {
        pk[i] =
            *(const int4*)(K + ((size_t)bh * 2048 + jn + kr) * 64 + kc + i * 8);
        pv[i] =
            *(const int4*)(Vt + ((size_t)bh * 64 + vd) * 2048 + jn + vc + i * 8);
      }
    }

    const int jbase = jb * 128;
    const bool last = (jb == jbmax);
#pragma unroll 2
    for (int kt = 0; kt < 8; ++kt) {
      const int kbase = jbase + kt * 16;
      if (kbase > wrow + 15) break;  // wave-uniform causal skip

      // St tile: A = K rows (m=k), B = Q rows (n=q)
      const u16* krow = &sK[(kt * 16 + l15) * 72 + quad * 8];
      bf16x8 ak0 = *(const bf16x8*)(krow);
      bf16x8 ak1 = *(const bf16x8*)(krow + 32);
      floatx4 st = (floatx4)0.0f;
      st = __builtin_amdgcn_mfma_f32_16x16x32_bf16(ak0, aq0, st, 0, 0, 0);
      st = __builtin_amdgcn_mfma_f32_16x16x32_bf16(ak1, aq1, st, 0, 0, 0);

      float p[4];
#pragma unroll
      for (int r = 0; r < 4; ++r) {
        float t = st[r] * 0.125f - 10.0f;  // 1/sqrt(64), fixed shift
        if (last && (kbase + quad * 4 + r > wrow + l15)) t = -1e30f;
        p[r] = __expf(t);
        lsum += p[r];
      }
      // P^T B-fragment: lane=q holds k=quad*4+r -> pack into j=0..3, zero-pad
      uint4 pfu{pk2(p[0], p[1]), pk2(p[2], p[3]), 0u, 0u};
      const bf16x8 pf8 = __builtin_bit_cast(bf16x8, pfu);

#pragma unroll
      for (int dt = 0; dt < 4; ++dt) {
        const u16* vp = &sV[(dt * 16 + l15) * 136 + kt * 16 + quad * 4];
        uint2 v2 = *(const uint2*)vp;  // 4 bf16 (k=quad*4..+3)
        uint4 avu{v2.x, v2.y, 0u, 0u};
        const bf16x8 av8 = __builtin_bit_cast(bf16x8, avu);
        accOT[dt] = __builtin_amdgcn_mfma_f32_16x16x32_bf16(av8, pf8,
                                                            accOT[dt], 0, 0, 0);
      }
    }
  }

  // total row sums: sum the 4 quad-partials (lanes sharing l15)
  lsum += __shfl_xor(lsum, 16, 64);
  lsum += __shfl_xor(lsum, 32, 64);
  const float inv = 1.0f / lsum;

  // epilogue: transpose O^T -> row-major via per-wave LDS tile, store ctx
  __syncthreads();  // everyone done reading sK this block
  u16* tw = &sK[w * 16 * 72];
#pragma unroll
  for (int dt = 0; dt < 4; ++dt) {
    uint2 o2{pk2(accOT[dt][0] * inv, accOT[dt][1] * inv),
             pk2(accOT[dt][2] * inv, accOT[dt][3] * inv)};
    *(uint2*)&tw[l15 * 72 + dt * 16 + quad * 4] = o2;
  }
  // per-wave write->read, in-wave DS ordering (round-12 precedent)
  const int b = bh >> 4, h = bh & 15;
  bf16x8 o0 = *(const bf16x8*)&tw[l15 * 72 + quad * 16];
  bf16x8 o1 = *(const bf16x8*)&tw[l15 * 72 + quad * 16 + 8];
  u16* cp = ctx + ((size_t)(b * 2048 + wrow + l15)) * 1024 + h * 64 + quad * 16;
  *(bf16x8*)cp = o0;
  *(bf16x8*)(cp + 8) = o1;
}

// ============================== launch ======================================
extern "C" void kernel_launch(void* const* d_in, const int* in_sizes, int n_in,
                              void* d_out, int out_size, void* d_ws,
                              size_t ws_size, hipStream_t stream) {
  const float* x = (const float*)d_in[0];
  const float* Wq = (const float*)d_in[1];
  const float* Wk = (const float*)d_in[2];
  const float* Wv = (const float*)d_in[3];
  const float* Wo = (const float*)d_in[4];
  const float* bo = (const float*)d_in[5];
  float* out = (float*)d_out;

  u16* Q = (u16*)d_ws;                  // 8 MB
  u16* K = Q + (size_t)4096 * 1024;     // 8 MB
  u16* Vt = K + (size_t)4096 * 1024;    // 8 MB
  u16* ctx = Vt + (size_t)4096 * 1024;  // 8 MB (shared slot with xb)

  if (ws_size >= (size_t)40 * 1024 * 1024) {
    // pre-converted bf16 path (m97-style gld_lds GEMMs)
    u16* xb = ctx;  // xb consumed by qkv before attn writes ctx
    u16* Wqb = (u16*)d_ws + (size_t)16 * 1024 * 1024;  // at 32 MB
    u16* Wkb = Wqb + (size_t)1024 * 1024;
    u16* Wvb = Wkb + (size_t)1024 * 1024;
    u16* Wob = Wvb + (size_t)1024 * 1024;              // ends at 40 MB

    cvt_all<<<4096, 256, 0, stream>>>(x, Wq, Wk, Wv, Wo, xb, Wqb, Wkb, Wvb,
                                      Wob);
    qkv_gemm_b<<<dim3(32, 24), 256, 0, stream>>>(xb, Wqb, Wkb, Wvb, Q, K, Vt);
    attn_kernel<<<1024, 256, 0, stream>>>(Q, K, Vt, ctx);
    out_gemm_b<<<dim3(32, 8), 256, 0, stream>>>(ctx, Wob, bo, out);
  } else {
    // fallback: f32-staging GEMMs (round-12 verified)
    qkv_gemm_f<<<dim3(32, 24), 256, 0, stream>>>(x, Wq, Wk, Wv, Q, K, Vt);
    attn_kernel<<<1024, 256, 0, stream>>>(Q, K, Vt, ctx);
    out_gemm_f<<<dim3(32, 8), 256, 0, stream>>>(ctx, Wo, bo, out);
  }
}

// Round 14
// 251.915 us; speedup vs baseline: 1.0561x; 1.0561x over previous
//
#include <hip/hip_runtime.h>
#include <hip/hip_bf16.h>

#define AS1 __attribute__((address_space(1)))
#define AS3 __attribute__((address_space(3)))

typedef __attribute__((ext_vector_type(4))) float floatx4;
typedef __attribute__((ext_vector_type(8))) short bf16x8;
typedef unsigned short u16;
typedef unsigned int u32;

// ---- bf16 helpers ----
__device__ __forceinline__ u16 f2b(float f) {  // RNE
  u32 u = __builtin_bit_cast(u32, f);
  u += 0x7fffu + ((u >> 16) & 1u);
  return (u16)(u >> 16);
}
__device__ __forceinline__ u32 pk2(float lo, float hi) {
  __hip_bfloat162 h = __float22bfloat162_rn(float2{lo, hi});
  u32 u;
  __builtin_memcpy(&u, &h, 4);
  return u;
}
__device__ __forceinline__ bf16x8 cvt8(float4 a, float4 b) {
  uint4 u{pk2(a.x, a.y), pk2(a.z, a.w), pk2(b.x, b.y), pk2(b.z, b.w)};
  return __builtin_bit_cast(bf16x8, u);
}

__device__ __forceinline__ void gld16(const void* g, AS3 u32* l) {
  __builtin_amdgcn_global_load_lds((const AS1 u32*)(const AS1 void*)g, l, 16,
                                   0, 0);
}

// ================= bulk f32 -> bf16 conversion (x + 4 weights) ==============
__global__ __launch_bounds__(256) void cvt_all(
    const float* __restrict__ x, const float* __restrict__ wq,
    const float* __restrict__ wk, const float* __restrict__ wv,
    const float* __restrict__ wo, u16* __restrict__ xb, u16* __restrict__ wqb,
    u16* __restrict__ wkb, u16* __restrict__ wvb, u16* __restrict__ wob) {
  const int i = blockIdx.x * 256 + threadIdx.x;  // handles 8 elems
  const float* src;
  u16* dst;
  int off;
  if (i < 524288) {
    src = x; dst = xb; off = i;
  } else {
    const int j = i - 524288;
    const int wsel = j >> 17;
    off = j & 131071;
    src = (wsel == 0) ? wq : (wsel == 1) ? wk : (wsel == 2) ? wv : wo;
    dst = (wsel == 0) ? wqb : (wsel == 1) ? wkb : (wsel == 2) ? wvb : wob;
  }
  const float4* p = (const float4*)(src + (size_t)off * 8);
  *(bf16x8*)(dst + (size_t)off * 8) = cvt8(p[0], p[1]);
}

// ====== bf16 128x128 GEMM mainloop (m97 pattern): global_load_lds w=16 ======
__device__ __forceinline__ void gemm_bf16(const u16* __restrict__ A,
                                          const u16* __restrict__ B, short* sA,
                                          short* sB, floatx4 acc[4][4]) {
  const int tid = threadIdx.x;
  const int lane = tid & 63;
  const int w = tid >> 6;
  const int l15 = lane & 15, quad = lane >> 4;
  const int wm = w >> 1, wn = w & 1;

  const u16* ga = A + ((size_t)(w * 32 + (lane >> 2))) * 1024 + (lane & 3) * 8;
  const u16* gb = B + ((size_t)(w * 32 + (lane >> 2))) * 1024 + (lane & 3) * 8;
  AS3 u32* la = (AS3 u32*)(AS3 short*)sA + w * 512;
  AS3 u32* lb = (AS3 u32*)(AS3 short*)sB + w * 512;

  for (int kt = 0; kt < 32; ++kt) {
    __syncthreads();
    gld16(ga, la);
    gld16(ga + (size_t)16 * 1024, la + 256);
    gld16(gb, lb);
    gld16(gb + (size_t)16 * 1024, lb + 256);
    ga += 32;
    gb += 32;
    __syncthreads();

    bf16x8 af[4], bfr[4];
#pragma unroll
    for (int mc = 0; mc < 4; ++mc)
      af[mc] = *(const bf16x8*)&sA[(wm * 64 + mc * 16 + l15) * 32 + quad * 8];
#pragma unroll
    for (int nc = 0; nc < 4; ++nc)
      bfr[nc] = *(const bf16x8*)&sB[(wn * 64 + nc * 16 + l15) * 32 + quad * 8];
#pragma unroll
    for (int mc = 0; mc < 4; ++mc)
#pragma unroll
      for (int nc = 0; nc < 4; ++nc)
        acc[mc][nc] = __builtin_amdgcn_mfma_f32_16x16x32_bf16(
            af[mc], bfr[nc], acc[mc][nc], 0, 0, 0);
  }
}

// ---------------- QKV epilogue (shared by both paths) -----------------------
__device__ __forceinline__ void qkv_epilogue(floatx4 acc[4][4], int m0, int nb,
                                             int sel, u16* __restrict__ Q,
                                             u16* __restrict__ K,
                                             u16* __restrict__ Vt) {
  const int tid = threadIdx.x;
  const int lane = tid & 63, w = tid >> 6;
  const int l15 = lane & 15, quad = lane >> 4;
  const int wm = w >> 1, wn = w & 1;
#pragma unroll
  for (int mc = 0; mc < 4; ++mc) {
#pragma unroll
    for (int nc = 0; nc < 4; ++nc) {
      const int nn = nb + wn * 64 + nc * 16 + l15;
      const int h = nn >> 6, d = nn & 63;
#pragma unroll
      for (int r = 0; r < 4; ++r) {
        const int m = m0 + wm * 64 + mc * 16 + quad * 4 + r;
        const int b = m >> 11, s = m & 2047;
        const int bh = b * 16 + h;
        const u16 v = f2b(acc[mc][nc][r]);
        if (sel == 0)
          Q[((size_t)bh * 2048 + s) * 64 + d] = v;
        else if (sel == 1)
          K[((size_t)bh * 2048 + s) * 64 + d] = v;
        else
          Vt[((size_t)bh * 64 + d) * 2048 + s] = v;
      }
    }
  }
}

__global__ __launch_bounds__(256) void qkv_gemm_b(
    const u16* __restrict__ xb, const u16* __restrict__ Wqb,
    const u16* __restrict__ Wkb, const u16* __restrict__ Wvb,
    u16* __restrict__ Q, u16* __restrict__ K, u16* __restrict__ Vt) {
  __shared__ __align__(16) short smem[2 * 128 * 32];
  const int m0 = blockIdx.x * 128;
  const int by = blockIdx.y;
  const int sel = by >> 3;
  const int nb = (by & 7) * 128;
  const u16* W = (sel == 0) ? Wqb : (sel == 1) ? Wkb : Wvb;

  floatx4 acc[4][4];
#pragma unroll
  for (int i = 0; i < 4; i++)
#pragma unroll
    for (int j = 0; j < 4; j++) acc[i][j] = (floatx4)0.0f;
  gemm_bf16(xb + (size_t)m0 * 1024, W + (size_t)nb * 1024, smem,
            smem + 128 * 32, acc);
  qkv_epilogue(acc, m0, nb, sel, Q, K, Vt);
}

__global__ __launch_bounds__(256) void out_gemm_b(const u16* __restrict__ ctx,
                                                  const u16* __restrict__ Wob,
                                                  const float* __restrict__ bo,
                                                  float* __restrict__ out) {
  __shared__ __align__(16) short smem[2 * 128 * 32];
  const int tid = threadIdx.x;
  const int lane = tid & 63, w = tid >> 6;
  const int l15 = lane & 15, quad = lane >> 4;
  const int wm = w >> 1, wn = w & 1;
  const int m0 = blockIdx.x * 128;
  const int n0 = blockIdx.y * 128;

  floatx4 acc[4][4];
#pragma unroll
  for (int i = 0; i < 4; i++)
#pragma unroll
    for (int j = 0; j < 4; j++) acc[i][j] = (floatx4)0.0f;
  gemm_bf16(ctx + (size_t)m0 * 1024, Wob + (size_t)n0 * 1024, smem,
            smem + 128 * 32, acc);

#pragma unroll
  for (int mc = 0; mc < 4; ++mc)
#pragma unroll
    for (int nc = 0; nc < 4; ++nc) {
      const int n = n0 + wn * 64 + nc * 16 + l15;
      const float bias = bo[n];
#pragma unroll
      for (int r = 0; r < 4; ++r) {
        const int m = m0 + wm * 64 + mc * 16 + quad * 4 + r;
        out[(size_t)m * 1024 + n] = acc[mc][nc][r] + bias;
      }
    }
}

// ============ Fallback f32-staging 128x128 GEMM (round-12, verified) ========
template <bool F32A>
__device__ __forceinline__ void gemm128(const void* __restrict__ A,
                                        const float* __restrict__ B, short* sA,
                                        short* sB, floatx4 acc[4][4]) {
  const int tid = threadIdx.x;
  const int lane = tid & 63;
  const int w = tid >> 6;
  const int l15 = lane & 15, quad = lane >> 4;
  const int wm = w >> 1, wn = w & 1;
  const int srow = tid >> 1;
  const int scb = (tid & 1) * 16;

  float4 pa[4], pb[4];
  int4 pa16[2];
  if constexpr (F32A) {
    const float* ap = (const float*)A + (size_t)srow * 1024 + scb;
    pa[0] = ((const float4*)ap)[0]; pa[1] = ((const float4*)ap)[1];
    pa[2] = ((const float4*)ap)[2]; pa[3] = ((const float4*)ap)[3];
  } else {
    const u16* ap = (const u16*)A + (size_t)srow * 1024 + scb;
    pa16[0] = ((const int4*)ap)[0]; pa16[1] = ((const int4*)ap)[1];
  }
  {
    const float* bp = B + (size_t)srow * 1024 + scb;
    pb[0] = ((const float4*)bp)[0]; pb[1] = ((const float4*)bp)[1];
    pb[2] = ((const float4*)bp)[2]; pb[3] = ((const float4*)bp)[3];
  }

  for (int kt = 0; kt < 32; ++kt) {
    __syncthreads();
    if constexpr (F32A) {
      *(bf16x8*)&sA[srow * 40 + scb] = cvt8(pa[0], pa[1]);
      *(bf16x8*)&sA[srow * 40 + scb + 8] = cvt8(pa[2], pa[3]);
    } else {
      *(int4*)&sA[srow * 40 + scb] = pa16[0];
      *(int4*)&sA[srow * 40 + scb + 8] = pa16[1];
    }
    *(bf16x8*)&sB[srow * 40 + scb] = cvt8(pb[0], pb[1]);
    *(bf16x8*)&sB[srow * 40 + scb + 8] = cvt8(pb[2], pb[3]);
    __syncthreads();

    if (kt < 31) {
      const int k0 = (kt + 1) * 32;
      if constexpr (F32A) {
        const float* ap = (const float*)A + (size_t)srow * 1024 + k0 + scb;
        pa[0] = ((const float4*)ap)[0]; pa[1] = ((const float4*)ap)[1];
        pa[2] = ((const float4*)ap)[2]; pa[3] = ((const float4*)ap)[3];
      } else {
        const u16* ap = (const u16*)A + (size_t)srow * 1024 + k0 + scb;
        pa16[0] = ((const int4*)ap)[0]; pa16[1] = ((const int4*)ap)[1];
      }
      const float* bp = B + (size_t)srow * 1024 + k0 + scb;
      pb[0] = ((const float4*)bp)[0]; pb[1] = ((const float4*)bp)[1];
      pb[2] = ((const float4*)bp)[2]; pb[3] = ((const float4*)bp)[3];
    }

    bf16x8 af[4], bfr[4];
#pragma unroll
    for (int mc = 0; mc < 4; ++mc)
      af[mc] = *(const bf16x8*)&sA[(wm * 64 + mc * 16 + l15) * 40 + quad * 8];
#pragma unroll
    for (int nc = 0; nc < 4; ++nc)
      bfr[nc] = *(const bf16x8*)&sB[(wn * 64 + nc * 16 + l15) * 40 + quad * 8];
#pragma unroll
    for (int mc = 0; mc < 4; ++mc)
#pragma unroll
      for (int nc = 0; nc < 4; ++nc)
        acc[mc][nc] = __builtin_amdgcn_mfma_f32_16x16x32_bf16(
            af[mc], bfr[nc], acc[mc][nc], 0, 0, 0);
  }
}

__global__ __launch_bounds__(256) void qkv_gemm_f(
    const float* __restrict__ x, const float* __restrict__ Wq,
    const float* __restrict__ Wk, const float* __restrict__ Wv,
    u16* __restrict__ Q, u16* __restrict__ K, u16* __restrict__ Vt) {
  __shared__ __align__(16) short smem[2 * 128 * 40];
  const int m0 = blockIdx.x * 128;
  const int by = blockIdx.y;
  const int sel = by >> 3;
  const int nb = (by & 7) * 128;
  const float* W = (sel == 0) ? Wq : (sel == 1) ? Wk : Wv;

  floatx4 acc[4][4];
#pragma unroll
  for (int i = 0; i < 4; i++)
#pragma unroll
    for (int j = 0; j < 4; j++) acc[i][j] = (floatx4)0.0f;
  gemm128<true>((const void*)(x + (size_t)m0 * 1024), W + (size_t)nb * 1024,
                smem, smem + 128 * 40, acc);
  qkv_epilogue(acc, m0, nb, sel, Q, K, Vt);
}

__global__ __launch_bounds__(256) void out_gemm_f(const u16* __restrict__ ctx,
                                                  const float* __restrict__ Wo,
                                                  const float* __restrict__ bo,
                                                  float* __restrict__ out) {
  __shared__ __align__(16) short smem[2 * 128 * 40];
  const int tid = threadIdx.x;
  const int lane = tid & 63, w = tid >> 6;
  const int l15 = lane & 15, quad = lane >> 4;
  const int wm = w >> 1, wn = w & 1;
  const int m0 = blockIdx.x * 128;
  const int n0 = blockIdx.y * 128;

  floatx4 acc[4][4];
#pragma unroll
  for (int i = 0; i < 4; i++)
#pragma unroll
    for (int j = 0; j < 4; j++) acc[i][j] = (floatx4)0.0f;
  gemm128<false>((const void*)(ctx + (size_t)m0 * 1024),
                 Wo + (size_t)n0 * 1024, smem, smem + 128 * 40, acc);

#pragma unroll
  for (int mc = 0; mc < 4; ++mc)
#pragma unroll
    for (int nc = 0; nc < 4; ++nc) {
      const int n = n0 + wn * 64 + nc * 16 + l15;
      const float bias = bo[n];
#pragma unroll
      for (int r = 0; r < 4; ++r) {
        const int m = m0 + wm * 64 + mc * 16 + quad * 4 + r;
        out[(size_t)m * 1024 + n] = acc[mc][nc][r] + bias;
      }
    }
}

// ============== Kernel: causal flash attention (transposed, 128q) ===========
// grid 512: qb=15-(bid>>5) (long first; bid%8==bh%8 keeps r12's XCD affinity),
// bh=bid&31. 128 q/block, wave owns 32 q as two 16-q column tiles.
// St = K*Q^T; C-layout(col=q,row=k) IS the PV B-operand -> no LDS round-trip.
// PV via zero-padded K=32 MFMA. Fixed-shift softmax (C=10). V-fragments
// loaded once per (kt,dt), reused across both q-tiles.
__global__ __launch_bounds__(256, 4) void attn_kernel(
    const u16* __restrict__ Q, const u16* __restrict__ K,
    const u16* __restrict__ Vt, u16* __restrict__ ctx) {
  const int bid = blockIdx.x;
  const int qb = 15 - (bid >> 5);
  const int bh = bid & 31;
  const int tid = threadIdx.x;
  const int w = tid >> 6;
  const int lane = tid & 63;
  const int l15 = lane & 15;
  const int quad = lane >> 4;

  __shared__ __align__(16) u16 sK[128 * 72];  // [key][d], pad 72
  __shared__ __align__(16) u16 sV[64 * 136];  // [d][key], pad 136

  const int q0 = qb * 128;
  const int wrow = q0 + w * 32;  // wave's 32 q rows

  bf16x8 aQ[2][2];
#pragma unroll
  for (int qt = 0; qt < 2; ++qt) {
    const u16* qp =
        Q + ((size_t)bh * 2048 + wrow + qt * 16 + l15) * 64 + quad * 8;
    aQ[qt][0] = *(const bf16x8*)(qp);
    aQ[qt][1] = *(const bf16x8*)(qp + 32);
  }

  floatx4 accOT[2][4];  // O^T per q-tile: col=q=l15, row=d=quad*4+r
#pragma unroll
  for (int qt = 0; qt < 2; ++qt)
#pragma unroll
    for (int i = 0; i < 4; ++i) accOT[qt][i] = (floatx4)0.0f;
  float lsum[2] = {0.0f, 0.0f};

  const int jbmax = qb;                          // (q0+127)>>7
  const int kr = tid >> 1, kc = (tid & 1) * 32;  // K staging
  const int vd = tid >> 2, vc = (tid & 3) * 32;  // V staging

  int4 pk[4], pv[4];
#pragma unroll
  for (int i = 0; i < 4; ++i) {
    pk[i] = *(const int4*)(K + ((size_t)bh * 2048 + kr) * 64 + kc + i * 8);
    pv[i] = *(const int4*)(Vt + ((size_t)bh * 64 + vd) * 2048 + vc + i * 8);
  }

  for (int jb = 0; jb <= jbmax; ++jb) {
    __syncthreads();  // prior tile reads complete
#pragma unroll
    for (int i = 0; i < 4; ++i) {
      *(int4*)&sK[kr * 72 + kc + i * 8] = pk[i];
      *(int4*)&sV[vd * 136 + vc + i * 8] = pv[i];
    }
    __syncthreads();  // staging visible
    if (jb < jbmax) {
      const int jn = (jb + 1) * 128;
#pragma unroll
      for (int i = 0; i < 4; ++i) {
        pk[i] =
            *(const int4*)(K + ((size_t)bh * 2048 + jn + kr) * 64 + kc + i * 8);
        pv[i] = *(const int4*)(Vt + ((size_t)bh * 64 + vd) * 2048 + jn + vc +
                               i * 8);
      }
    }

    const int jbase = jb * 128;
#pragma unroll 2
    for (int kt = 0; kt < 8; ++kt) {
      const int kbase = jbase + kt * 16;
      if (kbase > wrow + 31) break;  // wave-uniform causal skip

      const u16* krow = &sK[(kt * 16 + l15) * 72 + quad * 8];
      bf16x8 ak0 = *(const bf16x8*)(krow);
      bf16x8 ak1 = *(const bf16x8*)(krow + 32);

      // V fragments for this kt, shared by both q-tiles
      bf16x8 av8[4];
#pragma unroll
      for (int dt = 0; dt < 4; ++dt) {
        uint2 v2 =
            *(const uint2*)&sV[(dt * 16 + l15) * 136 + kt * 16 + quad * 4];
        uint4 avu{v2.x, v2.y, 0u, 0u};
        av8[dt] = __builtin_bit_cast(bf16x8, avu);
      }

#pragma unroll
      for (int qt = 0; qt < 2; ++qt) {
        const int qmin = wrow + qt * 16;
        if (kbase > qmin + 15) continue;  // this q-tile fully masked

        floatx4 st = (floatx4)0.0f;
        st = __builtin_amdgcn_mfma_f32_16x16x32_bf16(ak0, aQ[qt][0], st, 0, 0,
                                                     0);
        st = __builtin_amdgcn_mfma_f32_16x16x32_bf16(ak1, aQ[qt][1], st, 0, 0,
                                                     0);

        const bool need_mask = (kbase + 15 > qmin);  // wave-uniform
        float p[4];
#pragma unroll
        for (int r = 0; r < 4; ++r) {
          float t = st[r] * 0.125f - 10.0f;  // 1/sqrt(64), fixed shift
          if (need_mask && (kbase + quad * 4 + r > qmin + l15)) t = -1e30f;
          p[r] = __expf(t);
          lsum[qt] += p[r];
        }
        uint4 pfu{pk2(p[0], p[1]), pk2(p[2], p[3]), 0u, 0u};
        const bf16x8 pf8 = __builtin_bit_cast(bf16x8, pfu);

#pragma unroll
        for (int dt = 0; dt < 4; ++dt)
          accOT[qt][dt] = __builtin_amdgcn_mfma_f32_16x16x32_bf16(
              av8[dt], pf8, accOT[qt][dt], 0, 0, 0);
      }
    }
  }

  // total row sums: add the 4 quad-partials (lanes sharing l15)
#pragma unroll
  for (int qt = 0; qt < 2; ++qt) {
    lsum[qt] += __shfl_xor(lsum[qt], 16, 64);
    lsum[qt] += __shfl_xor(lsum[qt], 32, 64);
  }

  // epilogue: transpose O^T -> row-major via per-wave LDS chunk of sK
  __syncthreads();  // all waves done reading sK/sV
  const int b = bh >> 4, h = bh & 15;
#pragma unroll
  for (int qt = 0; qt < 2; ++qt) {
    const float inv = 1.0f / lsum[qt];
    u16* tw = &sK[(w * 32 + qt * 16) * 72];
#pragma unroll
    for (int dt = 0; dt < 4; ++dt) {
      uint2 o2{pk2(accOT[qt][dt][0] * inv, accOT[qt][dt][1] * inv),
               pk2(accOT[qt][dt][2] * inv, accOT[qt][dt][3] * inv)};
      *(uint2*)&tw[l15 * 72 + dt * 16 + quad * 4] = o2;
    }
    // in-wave write->read DS ordering
    bf16x8 o0 = *(const bf16x8*)&tw[l15 * 72 + quad * 16];
    bf16x8 o1 = *(const bf16x8*)&tw[l15 * 72 + quad * 16 + 8];
    u16* cp = ctx + ((size_t)(b * 2048 + wrow + qt * 16 + l15)) * 1024 +
              h * 64 + quad * 16;
    *(bf16x8*)cp = o0;
    *(bf16x8*)(cp + 8) = o1;
  }
}

// ============================== launch ======================================
extern "C" void kernel_launch(void* const* d_in, const int* in_sizes, int n_in,
                              void* d_out, int out_size, void* d_ws,
                              size_t ws_size, hipStream_t stream) {
  const float* x = (const float*)d_in[0];
  const float* Wq = (const float*)d_in[1];
  const float* Wk = (const float*)d_in[2];
  const float* Wv = (const float*)d_in[3];
  const float* Wo = (const float*)d_in[4];
  const float* bo = (const float*)d_in[5];
  float* out = (float*)d_out;

  u16* Q = (u16*)d_ws;                  // 8 MB
  u16* K = Q + (size_t)4096 * 1024;     // 8 MB
  u16* Vt = K + (size_t)4096 * 1024;    // 8 MB
  u16* ctx = Vt + (size_t)4096 * 1024;  // 8 MB (shared slot with xb)

  if (ws_size >= (size_t)40 * 1024 * 1024) {
    u16* xb = ctx;  // xb consumed by qkv before attn writes ctx
    u16* Wqb = (u16*)d_ws + (size_t)16 * 1024 * 1024;  // at 32 MB
    u16* Wkb = Wqb + (size_t)1024 * 1024;
    u16* Wvb = Wkb + (size_t)1024 * 1024;
    u16* Wob = Wvb + (size_t)1024 * 1024;  // ends at 40 MB

    cvt_all<<<4096, 256, 0, stream>>>(x, Wq, Wk, Wv, Wo, xb, Wqb, Wkb, Wvb,
                                      Wob);
    qkv_gemm_b<<<dim3(32, 24), 256, 0, stream>>>(xb, Wqb, Wkb, Wvb, Q, K, Vt);
    attn_kernel<<<512, 256, 0, stream>>>(Q, K, Vt, ctx);
    out_gemm_b<<<dim3(32, 8), 256, 0, stream>>>(ctx, Wob, bo, out);
  } else {
    qkv_gemm_f<<<dim3(32, 24), 256, 0, stream>>>(x, Wq, Wk, Wv, Q, K, Vt);
    attn_kernel<<<512, 256, 0, stream>>>(Q, K, Vt, ctx);
    out_gemm_f<<<dim3(32, 8), 256, 0, stream>>>(ctx, Wo, bo, out);
  }
}